// Round 6
// baseline (7661.470 us; speedup 1.0000x reference)
//
#include <hip/hip_runtime.h>
#include <hip/hip_fp8.h>
#include <hip/hip_fp16.h>
#include <stdint.h>

#define FP8_MAX_V 448.0f

typedef float f32x16 __attribute__((ext_vector_type(16)));
typedef int i32x4 __attribute__((ext_vector_type(4)));
typedef int i32x8 __attribute__((ext_vector_type(8)));

__device__ __forceinline__ uint8_t cvt_fp8(float v) {
    return __hip_cvt_float_to_fp8(fminf(fmaxf(v, -FP8_MAX_V), FP8_MAX_V),
                                  __HIP_SATFINITE, __HIP_E4M3);
}

// ---------------- amax (per-tensor, exact) ----------------
__global__ void fp8lin_init(unsigned* amax_bits) {
    *amax_bits = 0u;
}

__global__ void fp8lin_amax(const float4* __restrict__ x, unsigned* __restrict__ amax_bits, long n4) {
    float m = 0.f;
    long stride = (long)gridDim.x * blockDim.x;
    for (long i = blockIdx.x * (long)blockDim.x + threadIdx.x; i < n4; i += stride) {
        float4 v = x[i];
        m = fmaxf(m, fmaxf(fmaxf(fabsf(v.x), fabsf(v.y)), fmaxf(fabsf(v.z), fabsf(v.w))));
    }
#pragma unroll
    for (int o = 32; o; o >>= 1) m = fmaxf(m, __shfl_xor(m, o));
    if ((threadIdx.x & 63) == 0) atomicMax(amax_bits, __float_as_uint(m));
}

// ---------------- derive scales ONCE ----------------
__global__ void fp8lin_scales(const unsigned* __restrict__ amax_bits,
                              const float* __restrict__ wscale,
                              float* __restrict__ scales) {
    float xs = fmaxf(__uint_as_float(*amax_bits), 1e-12f) / FP8_MAX_V;
    scales[0] = xs;
    scales[1] = xs * wscale[0];
}

// ---------------- probe weight transport dtype ----------------
__global__ void fp8lin_probe(const uint32_t* __restrict__ w, unsigned* __restrict__ flag) {
    __shared__ unsigned s32, s16, s4;
    if (threadIdx.x == 0) { s32 = 0u; s16 = 0u; s4 = 0u; }
    __syncthreads();
    unsigned o32 = 0u, o16 = 0u, o4 = 0u;
    for (int i = threadIdx.x; i < 4096; i += 256) {
        uint32_t v = w[i];
        o32 |= v & 0x000FFFFFu;
        uint32_t h0 = v & 0xFFFFu, h1 = v >> 16;
        o16 |= (h0 & 0x7Fu) | (h1 & 0x7Fu);
        o4  |= (h0 & 0x0Fu) | (h1 & 0x0Fu);
    }
    atomicOr(&s32, o32); atomicOr(&s16, o16); atomicOr(&s4, o4);
    __syncthreads();
    if (threadIdx.x == 0)
        *flag = (s32 == 0u) ? 0u : (s16 == 0u) ? 1u : (s4 == 0u) ? 2u : 3u;
}

// ---------------- convert transported weight -> raw fp8 (exact) ----------------
__global__ void fp8lin_convw(const void* __restrict__ wsrc, const unsigned* __restrict__ flag,
                             uchar4* __restrict__ wq, long n4) {
    unsigned f = *flag;
    if (f == 3u) return;
    long stride = (long)gridDim.x * blockDim.x;
    if (f == 0u) {
        const float4* src = (const float4*)wsrc;
        for (long i = blockIdx.x * (long)blockDim.x + threadIdx.x; i < n4; i += stride) {
            float4 v = src[i];
            uchar4 o;
            o.x = cvt_fp8(v.x); o.y = cvt_fp8(v.y); o.z = cvt_fp8(v.z); o.w = cvt_fp8(v.w);
            wq[i] = o;
        }
    } else if (f == 1u) {
        const __half2* src = (const __half2*)wsrc;
        for (long i = blockIdx.x * (long)blockDim.x + threadIdx.x; i < n4; i += stride) {
            __half2 v0 = src[2 * i], v1 = src[2 * i + 1];
            uchar4 o;
            o.x = cvt_fp8(__half2float(v0.x)); o.y = cvt_fp8(__half2float(v0.y));
            o.z = cvt_fp8(__half2float(v1.x)); o.w = cvt_fp8(__half2float(v1.y));
            wq[i] = o;
        }
    } else {
        const ushort2* src = (const ushort2*)wsrc;
        for (long i = blockIdx.x * (long)blockDim.x + threadIdx.x; i < n4; i += stride) {
            ushort2 v0 = src[2 * i], v1 = src[2 * i + 1];
            uchar4 o;
            o.x = cvt_fp8(__uint_as_float((uint32_t)v0.x << 16));
            o.y = cvt_fp8(__uint_as_float((uint32_t)v0.y << 16));
            o.z = cvt_fp8(__uint_as_float((uint32_t)v1.x << 16));
            o.w = cvt_fp8(__uint_as_float((uint32_t)v1.y << 16));
            wq[i] = o;
        }
    }
}

// ---------------- quantize x -> fp8 e4m3fn ----------------
__global__ void fp8lin_quant(const float4* __restrict__ x, const float* __restrict__ scales,
                             uchar4* __restrict__ xq, long n4) {
    float s = scales[0];
    long stride = (long)gridDim.x * blockDim.x;
    for (long i = blockIdx.x * (long)blockDim.x + threadIdx.x; i < n4; i += stride) {
        float4 v = x[i];
        uchar4 o;
        o.x = cvt_fp8(v.x / s); o.y = cvt_fp8(v.y / s);
        o.z = cvt_fp8(v.z / s); o.w = cvt_fp8(v.w / s);
        xq[i] = o;
    }
}

// ---------------- fp8 GEMM: 256x256, BK=64, 8 waves, MX 32x32x64, double-buffer ----------------
#define BM 256
#define BN 256
#define BK 64
#define TILE_BYTES 16384              // 256 rows x 64 B
#define BUF_BYTES (2 * TILE_BYTES)    // A + B
#define SMEM_BYTES (2 * BUF_BYTES)    // 64 KiB double-buffered -> 2 blocks/CU

__device__ __forceinline__ void gload16(const uint8_t* src, uint8_t* ldst) {
    __builtin_amdgcn_global_load_lds(
        (const __attribute__((address_space(1))) uint32_t*)(uintptr_t)src,
        (__attribute__((address_space(3))) uint32_t*)(uintptr_t)ldst, 16, 0, 0);
}

#define WAITVM(N) asm volatile("s_waitcnt vmcnt(" #N ")" ::: "memory")
#define BARRIER() do { asm volatile("" ::: "memory"); __builtin_amdgcn_s_barrier(); \
                       asm volatile("" ::: "memory"); } while (0)

// load one 32B k-fragment (two ds_read_b128 at XOR-16 swizzled granules)
#define LDFRAG(dst, base, off) do {                                    \
    i32x4 _lo = *(const i32x4*)((base) + (off));                       \
    i32x4 _hi = *(const i32x4*)((base) + ((off) ^ 16));                \
    dst[0] = _lo[0]; dst[1] = _lo[1]; dst[2] = _lo[2]; dst[3] = _lo[3];\
    dst[4] = _hi[0]; dst[5] = _hi[1]; dst[6] = _hi[2]; dst[7] = _hi[3];\
} while (0)

// unit scales: e8m0 byte 0x7f = 2^0, every byte identical so opsel-immune
#define MFMA_MX(A, B, C) __builtin_amdgcn_mfma_scale_f32_32x32x64_f8f6f4( \
    (A), (B), (C), 0, 0, 0, (int)0x7f7f7f7f, 0, (int)0x7f7f7f7f)

__global__ __launch_bounds__(512, 4) void fp8lin_gemm(
    const uint8_t* __restrict__ Aq,    // [M,K] fp8
    const uint8_t* __restrict__ Wraw,  // original weight ptr (valid iff flag==3)
    const uint8_t* __restrict__ Wconv, // converted fp8 (valid iff flag!=3)
    const unsigned* __restrict__ flag,
    const float* __restrict__ scales,
    const float* __restrict__ bias,
    float* __restrict__ out,
    int M, int N, int K) {
    extern __shared__ __align__(16) uint8_t smem[];

    const uint8_t* __restrict__ Wq = (*flag == 3u) ? Wraw : Wconv;

    const int tid = threadIdx.x;
    const int wid = tid >> 6;
    const int lane = tid & 63;
    const int wm = wid >> 2;   // 0..1  (M-wave, 128 rows each)
    const int wn = wid & 3;    // 0..3  (N-wave, 64 cols each)

    // ---- bijective XCD swizzle: each XCD owns 4 contiguous brow-rows ----
    const int nbx = gridDim.x;                       // 64
    const int orig = blockIdx.y * nbx + blockIdx.x;  // dispatch order
    const int cpx = (gridDim.x * gridDim.y) >> 3;    // 256
    const int swzb = (orig & 7) * cpx + (orig >> 3);
    const int brow = (swzb / nbx) * BM;
    const int bcol = (swzb % nbx) * BN;

    // ---- staging: LDS linear [row][4 granules]; granule p holds global
    // granule p ^ ((row>>1)&3)  => pre-swizzle the global source column ----
    const int c0 = tid, c1 = tid + 512;
    const int rS0 = c0 >> 2, rS1 = c1 >> 2;
    const int scS0 = ((c0 & 3) ^ ((rS0 >> 1) & 3)) * 16;
    const int scS1 = ((c1 & 3) ^ ((rS1 >> 1) & 3)) * 16;
    const uint8_t* srcA0 = Aq + (size_t)(brow + rS0) * K + scS0;
    const uint8_t* srcA1 = Aq + (size_t)(brow + rS1) * K + scS1;
    const uint8_t* srcB0 = Wq + (size_t)(bcol + rS0) * K + scS0;
    const uint8_t* srcB1 = Wq + (size_t)(bcol + rS1) * K + scS1;
    const int ldsJ0 = wid * 1024;
    const int ldsJ1 = wid * 1024 + 8192;

    // ---- ds_read addressing: lane reads k-bytes [32q,32q+32) of its row ----
    const int l31 = lane & 31;
    const int q = lane >> 5;
    const int swzr = (l31 >> 1) & 3;          // row-base is mult of 32
    const int posl = (2 * q) ^ swzr;
    const int offA = (wm * 128 + l31) * 64 + posl * 16;  // + mi*2048
    const int offB = (wn * 64 + l31) * 64 + posl * 16;   // + ni*2048

    f32x16 acc[4][2];
#pragma unroll
    for (int mi = 0; mi < 4; ++mi)
#pragma unroll
        for (int ni = 0; ni < 2; ++ni)
#pragma unroll
            for (int r = 0; r < 16; ++r) acc[mi][ni][r] = 0.0f;

    auto STAGE = [&](int t, int ib) {
        size_t k0 = (size_t)t * BK;
        uint8_t* base = smem + ib * BUF_BYTES;
        gload16(srcA0 + k0, base + ldsJ0);
        gload16(srcA1 + k0, base + ldsJ1);
        gload16(srcB0 + k0, base + TILE_BYTES + ldsJ0);
        gload16(srcB1 + k0, base + TILE_BYTES + ldsJ1);
    };

    auto COMPUTE = [&](int ib) {
        const uint8_t* bA = smem + ib * BUF_BYTES;
        const uint8_t* bB = bA + TILE_BYTES;
        i32x8 a0, a1, a2, a3, b0, b1;
        LDFRAG(a0, bA, offA);
        LDFRAG(a1, bA, offA + 2048);
        LDFRAG(b0, bB, offB);
        LDFRAG(b1, bB, offB + 2048);
        __builtin_amdgcn_s_setprio(1);
        acc[0][0] = MFMA_MX(a0, b0, acc[0][0]);
        acc[1][0] = MFMA_MX(a1, b0, acc[1][0]);
        acc[0][1] = MFMA_MX(a0, b1, acc[0][1]);
        acc[1][1] = MFMA_MX(a1, b1, acc[1][1]);
        __builtin_amdgcn_s_setprio(0);
        LDFRAG(a2, bA, offA + 4096);
        LDFRAG(a3, bA, offA + 6144);
        __builtin_amdgcn_s_setprio(1);
        acc[2][0] = MFMA_MX(a2, b0, acc[2][0]);
        acc[3][0] = MFMA_MX(a3, b0, acc[3][0]);
        acc[2][1] = MFMA_MX(a2, b1, acc[2][1]);
        acc[3][1] = MFMA_MX(a3, b1, acc[3][1]);
        __builtin_amdgcn_s_setprio(0);
    };

    const int NT = K / BK;  // 64
    STAGE(0, 0);
    int cur = 0;
    for (int t = 0; t < NT - 1; ++t) {
        STAGE(t + 1, cur ^ 1);   // issue next tile's loads (1-tile cover ~1500cy > 900cy HBM)
        WAITVM(4);               // tile t's 4 loads landed; next tile's stay in flight
        BARRIER();
        COMPUTE(cur);
        BARRIER();               // all LDS reads of buf cur retired before restaging
        cur ^= 1;
    }
    WAITVM(0);
    BARRIER();
    COMPUTE(cur);

    // ---- epilogue: 32x32 C/D layout col=lane&31, row=(reg&3)+8*(reg>>2)+4*q ----
    // nontemporal: output is write-once, keep it from evicting B in L2/L3
    float s = scales[1];
    const int colg = bcol + wn * 64 + l31;
    const int rowg0 = brow + wm * 128 + 4 * q;
#pragma unroll
    for (int ni = 0; ni < 2; ++ni) {
        int col = colg + ni * 32;
        float bv = bias[col];
#pragma unroll
        for (int mi = 0; mi < 4; ++mi) {
            int rb = rowg0 + mi * 32;
#pragma unroll
            for (int reg = 0; reg < 16; ++reg) {
                int row = rb + (reg & 3) + 8 * (reg >> 2);
                __builtin_nontemporal_store(acc[mi][ni][reg] * s + bv,
                                            out + (size_t)row * N + col);
            }
        }
    }
}

extern "C" void kernel_launch(void* const* d_in, const int* in_sizes, int n_in,
                              void* d_out, int out_size, void* d_ws, size_t ws_size,
                              hipStream_t stream) {
    const float* x = (const float*)d_in[0];
    const void* w = d_in[1];
    const float* wscale = (const float*)d_in[2];
    const float* bias = (const float*)d_in[3];
    float* out = (float*)d_out;

    const int Bb = 4, S = 2048, K = 4096, N = 16384;
    const int M = Bb * S;
    const long nx = (long)M * K;
    const long nw = (long)N * K;

    unsigned* amax_bits = (unsigned*)d_ws;
    float* scales = (float*)((char*)d_ws + 16);
    unsigned* wflag = (unsigned*)((char*)d_ws + 32);
    uchar4* xq = (uchar4*)((char*)d_ws + 256);
    uchar4* wq = (uchar4*)((char*)d_ws + 256 + nx);

    fp8lin_init<<<1, 1, 0, stream>>>(amax_bits);
    fp8lin_probe<<<1, 256, 0, stream>>>((const uint32_t*)w, wflag);
    fp8lin_amax<<<2048, 256, 0, stream>>>((const float4*)x, amax_bits, nx / 4);
    fp8lin_scales<<<1, 1, 0, stream>>>(amax_bits, wscale, scales);
    fp8lin_quant<<<2048, 256, 0, stream>>>((const float4*)x, scales, xq, nx / 4);
    fp8lin_convw<<<2048, 256, 0, stream>>>(w, wflag, wq, nw / 4);

    dim3 grid(N / BN, M / BM);
    fp8lin_gemm<<<grid, 512, SMEM_BYTES, stream>>>((const uint8_t*)xq, (const uint8_t*)w,
                                                   (const uint8_t*)wq, wflag, scales, bias, out,
                                                   M, N, K);
}

// Round 7
// 793.780 us; speedup vs baseline: 9.6519x; 9.6519x over previous
//
#include <hip/hip_runtime.h>
#include <hip/hip_fp8.h>
#include <hip/hip_fp16.h>
#include <stdint.h>

#define FP8_MAX_V 448.0f

typedef float f32x16 __attribute__((ext_vector_type(16)));
typedef int i32x4 __attribute__((ext_vector_type(4)));
typedef int i32x8 __attribute__((ext_vector_type(8)));

__device__ __forceinline__ uint8_t cvt_fp8(float v) {
    return __hip_cvt_float_to_fp8(fminf(fmaxf(v, -FP8_MAX_V), FP8_MAX_V),
                                  __HIP_SATFINITE, __HIP_E4M3);
}

// ---------------- amax (per-tensor, exact) ----------------
__global__ void fp8lin_init(unsigned* amax_bits) {
    *amax_bits = 0u;
}

__global__ void fp8lin_amax(const float4* __restrict__ x, unsigned* __restrict__ amax_bits, long n4) {
    float m = 0.f;
    long stride = (long)gridDim.x * blockDim.x;
    for (long i = blockIdx.x * (long)blockDim.x + threadIdx.x; i < n4; i += stride) {
        float4 v = x[i];
        m = fmaxf(m, fmaxf(fmaxf(fabsf(v.x), fabsf(v.y)), fmaxf(fabsf(v.z), fabsf(v.w))));
    }
#pragma unroll
    for (int o = 32; o; o >>= 1) m = fmaxf(m, __shfl_xor(m, o));
    if ((threadIdx.x & 63) == 0) atomicMax(amax_bits, __float_as_uint(m));
}

// ---------------- derive scales ONCE ----------------
__global__ void fp8lin_scales(const unsigned* __restrict__ amax_bits,
                              const float* __restrict__ wscale,
                              float* __restrict__ scales) {
    float xs = fmaxf(__uint_as_float(*amax_bits), 1e-12f) / FP8_MAX_V;
    scales[0] = xs;
    scales[1] = xs * wscale[0];
}

// ---------------- probe weight transport dtype ----------------
__global__ void fp8lin_probe(const uint32_t* __restrict__ w, unsigned* __restrict__ flag) {
    __shared__ unsigned s32, s16, s4;
    if (threadIdx.x == 0) { s32 = 0u; s16 = 0u; s4 = 0u; }
    __syncthreads();
    unsigned o32 = 0u, o16 = 0u, o4 = 0u;
    for (int i = threadIdx.x; i < 4096; i += 256) {
        uint32_t v = w[i];
        o32 |= v & 0x000FFFFFu;
        uint32_t h0 = v & 0xFFFFu, h1 = v >> 16;
        o16 |= (h0 & 0x7Fu) | (h1 & 0x7Fu);
        o4  |= (h0 & 0x0Fu) | (h1 & 0x0Fu);
    }
    atomicOr(&s32, o32); atomicOr(&s16, o16); atomicOr(&s4, o4);
    __syncthreads();
    if (threadIdx.x == 0)
        *flag = (s32 == 0u) ? 0u : (s16 == 0u) ? 1u : (s4 == 0u) ? 2u : 3u;
}

// ---------------- convert transported weight -> raw fp8 (exact) ----------------
__global__ void fp8lin_convw(const void* __restrict__ wsrc, const unsigned* __restrict__ flag,
                             uchar4* __restrict__ wq, long n4) {
    unsigned f = *flag;
    if (f == 3u) return;
    long stride = (long)gridDim.x * blockDim.x;
    if (f == 0u) {
        const float4* src = (const float4*)wsrc;
        for (long i = blockIdx.x * (long)blockDim.x + threadIdx.x; i < n4; i += stride) {
            float4 v = src[i];
            uchar4 o;
            o.x = cvt_fp8(v.x); o.y = cvt_fp8(v.y); o.z = cvt_fp8(v.z); o.w = cvt_fp8(v.w);
            wq[i] = o;
        }
    } else if (f == 1u) {
        const __half2* src = (const __half2*)wsrc;
        for (long i = blockIdx.x * (long)blockDim.x + threadIdx.x; i < n4; i += stride) {
            __half2 v0 = src[2 * i], v1 = src[2 * i + 1];
            uchar4 o;
            o.x = cvt_fp8(__half2float(v0.x)); o.y = cvt_fp8(__half2float(v0.y));
            o.z = cvt_fp8(__half2float(v1.x)); o.w = cvt_fp8(__half2float(v1.y));
            wq[i] = o;
        }
    } else {
        const ushort2* src = (const ushort2*)wsrc;
        for (long i = blockIdx.x * (long)blockDim.x + threadIdx.x; i < n4; i += stride) {
            ushort2 v0 = src[2 * i], v1 = src[2 * i + 1];
            uchar4 o;
            o.x = cvt_fp8(__uint_as_float((uint32_t)v0.x << 16));
            o.y = cvt_fp8(__uint_as_float((uint32_t)v0.y << 16));
            o.z = cvt_fp8(__uint_as_float((uint32_t)v1.x << 16));
            o.w = cvt_fp8(__uint_as_float((uint32_t)v1.y << 16));
            wq[i] = o;
        }
    }
}

// ---------------- quantize x -> fp8 e4m3fn ----------------
__global__ void fp8lin_quant(const float4* __restrict__ x, const float* __restrict__ scales,
                             uchar4* __restrict__ xq, long n4) {
    float s = scales[0];
    long stride = (long)gridDim.x * blockDim.x;
    for (long i = blockIdx.x * (long)blockDim.x + threadIdx.x; i < n4; i += stride) {
        float4 v = x[i];
        uchar4 o;
        o.x = cvt_fp8(v.x / s); o.y = cvt_fp8(v.y / s);
        o.z = cvt_fp8(v.z / s); o.w = cvt_fp8(v.w / s);
        xq[i] = o;
    }
}

// ---------------- fp8 GEMM: 256x256, BK=64, 8 waves, MX 32x32x64, double-buffer ----------------
#define BM 256
#define BN 256
#define BK 64
#define TILE_BYTES 16384              // 256 rows x 64 B
#define BUF_BYTES (2 * TILE_BYTES)    // A + B
#define SMEM_BYTES (2 * BUF_BYTES)    // 64 KiB double-buffered -> 2 blocks/CU

__device__ __forceinline__ void gload16(const uint8_t* src, uint8_t* ldst) {
    __builtin_amdgcn_global_load_lds(
        (const __attribute__((address_space(1))) uint32_t*)(uintptr_t)src,
        (__attribute__((address_space(3))) uint32_t*)(uintptr_t)ldst, 16, 0, 0);
}

#define WAITVM(N) asm volatile("s_waitcnt vmcnt(" #N ")" ::: "memory")
#define BARRIER() do { asm volatile("" ::: "memory"); __builtin_amdgcn_s_barrier(); \
                       asm volatile("" ::: "memory"); } while (0)

// load one 32B k-fragment (two ds_read_b128 at XOR-16 swizzled granules)
#define LDFRAG(dst, base, off) do {                                    \
    i32x4 _lo = *(const i32x4*)((base) + (off));                       \
    i32x4 _hi = *(const i32x4*)((base) + ((off) ^ 16));                \
    dst[0] = _lo[0]; dst[1] = _lo[1]; dst[2] = _lo[2]; dst[3] = _lo[3];\
    dst[4] = _hi[0]; dst[5] = _hi[1]; dst[6] = _hi[2]; dst[7] = _hi[3];\
} while (0)

// unit scales: e8m0 byte 0x7f = 2^0, every byte identical so opsel-immune
#define MFMA_MX(A, B, C) __builtin_amdgcn_mfma_scale_f32_32x32x64_f8f6f4( \
    (A), (B), (C), 0, 0, 0, (int)0x7f7f7f7f, 0, (int)0x7f7f7f7f)

// NOTE: min-waves/EU = 2 (256-reg budget). Forcing 4 made the allocator spill
// the 128-reg accumulator to scratch: 39.6 GB/dispatch, 11x regression (R6).
__global__ __launch_bounds__(512, 2) void fp8lin_gemm(
    const uint8_t* __restrict__ Aq,    // [M,K] fp8
    const uint8_t* __restrict__ Wraw,  // original weight ptr (valid iff flag==3)
    const uint8_t* __restrict__ Wconv, // converted fp8 (valid iff flag!=3)
    const unsigned* __restrict__ flag,
    const float* __restrict__ scales,
    const float* __restrict__ bias,
    float* __restrict__ out,
    int M, int N, int K) {
    extern __shared__ __align__(16) uint8_t smem[];

    const uint8_t* __restrict__ Wq = (*flag == 3u) ? Wraw : Wconv;

    const int tid = threadIdx.x;
    const int wid = tid >> 6;
    const int lane = tid & 63;
    const int wm = wid >> 2;   // 0..1  (M-wave, 128 rows each)
    const int wn = wid & 3;    // 0..3  (N-wave, 64 cols each)

    // ---- bijective XCD swizzle: each XCD owns 4 contiguous brow-rows ----
    const int nbx = gridDim.x;                       // 64
    const int orig = blockIdx.y * nbx + blockIdx.x;  // dispatch order
    const int cpx = (gridDim.x * gridDim.y) >> 3;    // 256
    const int swzb = (orig & 7) * cpx + (orig >> 3);
    const int brow = (swzb / nbx) * BM;
    const int bcol = (swzb % nbx) * BN;

    // ---- staging: LDS linear [row][4 granules]; granule p holds global
    // granule p ^ ((row>>1)&3)  => pre-swizzle the global source column ----
    const int c0 = tid, c1 = tid + 512;
    const int rS0 = c0 >> 2, rS1 = c1 >> 2;
    const int scS0 = ((c0 & 3) ^ ((rS0 >> 1) & 3)) * 16;
    const int scS1 = ((c1 & 3) ^ ((rS1 >> 1) & 3)) * 16;
    const uint8_t* srcA0 = Aq + (size_t)(brow + rS0) * K + scS0;
    const uint8_t* srcA1 = Aq + (size_t)(brow + rS1) * K + scS1;
    const uint8_t* srcB0 = Wq + (size_t)(bcol + rS0) * K + scS0;
    const uint8_t* srcB1 = Wq + (size_t)(bcol + rS1) * K + scS1;
    const int ldsJ0 = wid * 1024;
    const int ldsJ1 = wid * 1024 + 8192;

    // ---- ds_read addressing: lane reads k-bytes [32q,32q+32) of its row ----
    const int l31 = lane & 31;
    const int q = lane >> 5;
    const int swzr = (l31 >> 1) & 3;          // row-base is mult of 32
    const int posl = (2 * q) ^ swzr;
    const int offA = (wm * 128 + l31) * 64 + posl * 16;  // + mi*2048
    const int offB = (wn * 64 + l31) * 64 + posl * 16;   // + ni*2048

    f32x16 acc[4][2];
#pragma unroll
    for (int mi = 0; mi < 4; ++mi)
#pragma unroll
        for (int ni = 0; ni < 2; ++ni)
#pragma unroll
            for (int r = 0; r < 16; ++r) acc[mi][ni][r] = 0.0f;

    auto STAGE = [&](int t, int ib) {
        size_t k0 = (size_t)t * BK;
        uint8_t* base = smem + ib * BUF_BYTES;
        gload16(srcA0 + k0, base + ldsJ0);
        gload16(srcA1 + k0, base + ldsJ1);
        gload16(srcB0 + k0, base + TILE_BYTES + ldsJ0);
        gload16(srcB1 + k0, base + TILE_BYTES + ldsJ1);
    };

    auto COMPUTE = [&](int ib) {
        const uint8_t* bA = smem + ib * BUF_BYTES;
        const uint8_t* bB = bA + TILE_BYTES;
        i32x8 a0, a1, a2, a3, b0, b1;
        LDFRAG(a0, bA, offA);
        LDFRAG(a1, bA, offA + 2048);
        LDFRAG(b0, bB, offB);
        LDFRAG(b1, bB, offB + 2048);
        __builtin_amdgcn_s_setprio(1);
        acc[0][0] = MFMA_MX(a0, b0, acc[0][0]);
        acc[1][0] = MFMA_MX(a1, b0, acc[1][0]);
        acc[0][1] = MFMA_MX(a0, b1, acc[0][1]);
        acc[1][1] = MFMA_MX(a1, b1, acc[1][1]);
        __builtin_amdgcn_s_setprio(0);
        LDFRAG(a2, bA, offA + 4096);
        LDFRAG(a3, bA, offA + 6144);
        __builtin_amdgcn_s_setprio(1);
        acc[2][0] = MFMA_MX(a2, b0, acc[2][0]);
        acc[3][0] = MFMA_MX(a3, b0, acc[3][0]);
        acc[2][1] = MFMA_MX(a2, b1, acc[2][1]);
        acc[3][1] = MFMA_MX(a3, b1, acc[3][1]);
        __builtin_amdgcn_s_setprio(0);
    };

    const int NT = K / BK;  // 64
    STAGE(0, 0);
    int cur = 0;
    for (int t = 0; t < NT - 1; ++t) {
        STAGE(t + 1, cur ^ 1);   // issue next tile's loads (1-tile cover ~1500cy > 900cy HBM)
        WAITVM(4);               // tile t's 4 loads landed; next tile's stay in flight
        BARRIER();
        COMPUTE(cur);
        BARRIER();               // all LDS reads of buf cur retired before restaging
        cur ^= 1;
    }
    WAITVM(0);
    BARRIER();
    COMPUTE(cur);

    // ---- epilogue: 32x32 C/D layout col=lane&31, row=(reg&3)+8*(reg>>2)+4*q ----
    // nontemporal: output is write-once, keep it from evicting B in L2/L3
    float s = scales[1];
    const int colg = bcol + wn * 64 + l31;
    const int rowg0 = brow + wm * 128 + 4 * q;
#pragma unroll
    for (int ni = 0; ni < 2; ++ni) {
        int col = colg + ni * 32;
        float bv = bias[col];
#pragma unroll
        for (int mi = 0; mi < 4; ++mi) {
            int rb = rowg0 + mi * 32;
#pragma unroll
            for (int reg = 0; reg < 16; ++reg) {
                int row = rb + (reg & 3) + 8 * (reg >> 2);
                __builtin_nontemporal_store(acc[mi][ni][reg] * s + bv,
                                            out + (size_t)row * N + col);
            }
        }
    }
}

extern "C" void kernel_launch(void* const* d_in, const int* in_sizes, int n_in,
                              void* d_out, int out_size, void* d_ws, size_t ws_size,
                              hipStream_t stream) {
    const float* x = (const float*)d_in[0];
    const void* w = d_in[1];
    const float* wscale = (const float*)d_in[2];
    const float* bias = (const float*)d_in[3];
    float* out = (float*)d_out;

    const int Bb = 4, S = 2048, K = 4096, N = 16384;
    const int M = Bb * S;
    const long nx = (long)M * K;
    const long nw = (long)N * K;

    unsigned* amax_bits = (unsigned*)d_ws;
    float* scales = (float*)((char*)d_ws + 16);
    unsigned* wflag = (unsigned*)((char*)d_ws + 32);
    uchar4* xq = (uchar4*)((char*)d_ws + 256);
    uchar4* wq = (uchar4*)((char*)d_ws + 256 + nx);

    fp8lin_init<<<1, 1, 0, stream>>>(amax_bits);
    fp8lin_probe<<<1, 256, 0, stream>>>((const uint32_t*)w, wflag);
    fp8lin_amax<<<2048, 256, 0, stream>>>((const float4*)x, amax_bits, nx / 4);
    fp8lin_scales<<<1, 1, 0, stream>>>(amax_bits, wscale, scales);
    fp8lin_quant<<<2048, 256, 0, stream>>>((const float4*)x, scales, xq, nx / 4);
    fp8lin_convw<<<2048, 256, 0, stream>>>(w, wflag, wq, nw / 4);

    dim3 grid(N / BN, M / BM);
    fp8lin_gemm<<<grid, 512, SMEM_BYTES, stream>>>((const uint8_t*)xq, (const uint8_t*)w,
                                                   (const uint8_t*)wq, wflag, scales, bias, out,
                                                   M, N, K);
}

// Round 8
// 778.523 us; speedup vs baseline: 9.8410x; 1.0196x over previous
//
#include <hip/hip_runtime.h>
#include <hip/hip_fp8.h>
#include <hip/hip_fp16.h>
#include <stdint.h>

#define FP8_MAX_V 448.0f

typedef float f32x16 __attribute__((ext_vector_type(16)));
typedef int i32x4 __attribute__((ext_vector_type(4)));
typedef int i32x8 __attribute__((ext_vector_type(8)));

__device__ __forceinline__ uint8_t cvt_fp8(float v) {
    return __hip_cvt_float_to_fp8(fminf(fmaxf(v, -FP8_MAX_V), FP8_MAX_V),
                                  __HIP_SATFINITE, __HIP_E4M3);
}

// ---------------- amax (per-tensor, exact) ----------------
__global__ void fp8lin_init(unsigned* amax_bits) {
    *amax_bits = 0u;
}

__global__ void fp8lin_amax(const float4* __restrict__ x, unsigned* __restrict__ amax_bits, long n4) {
    float m = 0.f;
    long stride = (long)gridDim.x * blockDim.x;
    for (long i = blockIdx.x * (long)blockDim.x + threadIdx.x; i < n4; i += stride) {
        float4 v = x[i];
        m = fmaxf(m, fmaxf(fmaxf(fabsf(v.x), fabsf(v.y)), fmaxf(fabsf(v.z), fabsf(v.w))));
    }
#pragma unroll
    for (int o = 32; o; o >>= 1) m = fmaxf(m, __shfl_xor(m, o));
    if ((threadIdx.x & 63) == 0) atomicMax(amax_bits, __float_as_uint(m));
}

// ---------------- derive scales ONCE ----------------
__global__ void fp8lin_scales(const unsigned* __restrict__ amax_bits,
                              const float* __restrict__ wscale,
                              float* __restrict__ scales) {
    float xs = fmaxf(__uint_as_float(*amax_bits), 1e-12f) / FP8_MAX_V;
    scales[0] = xs;
    scales[1] = xs * wscale[0];
}

// ---------------- probe weight transport dtype ----------------
__global__ void fp8lin_probe(const uint32_t* __restrict__ w, unsigned* __restrict__ flag) {
    __shared__ unsigned s32, s16, s4;
    if (threadIdx.x == 0) { s32 = 0u; s16 = 0u; s4 = 0u; }
    __syncthreads();
    unsigned o32 = 0u, o16 = 0u, o4 = 0u;
    for (int i = threadIdx.x; i < 4096; i += 256) {
        uint32_t v = w[i];
        o32 |= v & 0x000FFFFFu;
        uint32_t h0 = v & 0xFFFFu, h1 = v >> 16;
        o16 |= (h0 & 0x7Fu) | (h1 & 0x7Fu);
        o4  |= (h0 & 0x0Fu) | (h1 & 0x0Fu);
    }
    atomicOr(&s32, o32); atomicOr(&s16, o16); atomicOr(&s4, o4);
    __syncthreads();
    if (threadIdx.x == 0)
        *flag = (s32 == 0u) ? 0u : (s16 == 0u) ? 1u : (s4 == 0u) ? 2u : 3u;
}

// ---------------- convert transported weight -> raw fp8 (exact) ----------------
__global__ void fp8lin_convw(const void* __restrict__ wsrc, const unsigned* __restrict__ flag,
                             uchar4* __restrict__ wq, long n4) {
    unsigned f = *flag;
    if (f == 3u) return;
    long stride = (long)gridDim.x * blockDim.x;
    if (f == 0u) {
        const float4* src = (const float4*)wsrc;
        for (long i = blockIdx.x * (long)blockDim.x + threadIdx.x; i < n4; i += stride) {
            float4 v = src[i];
            uchar4 o;
            o.x = cvt_fp8(v.x); o.y = cvt_fp8(v.y); o.z = cvt_fp8(v.z); o.w = cvt_fp8(v.w);
            wq[i] = o;
        }
    } else if (f == 1u) {
        const __half2* src = (const __half2*)wsrc;
        for (long i = blockIdx.x * (long)blockDim.x + threadIdx.x; i < n4; i += stride) {
            __half2 v0 = src[2 * i], v1 = src[2 * i + 1];
            uchar4 o;
            o.x = cvt_fp8(__half2float(v0.x)); o.y = cvt_fp8(__half2float(v0.y));
            o.z = cvt_fp8(__half2float(v1.x)); o.w = cvt_fp8(__half2float(v1.y));
            wq[i] = o;
        }
    } else {
        const ushort2* src = (const ushort2*)wsrc;
        for (long i = blockIdx.x * (long)blockDim.x + threadIdx.x; i < n4; i += stride) {
            ushort2 v0 = src[2 * i], v1 = src[2 * i + 1];
            uchar4 o;
            o.x = cvt_fp8(__uint_as_float((uint32_t)v0.x << 16));
            o.y = cvt_fp8(__uint_as_float((uint32_t)v0.y << 16));
            o.z = cvt_fp8(__uint_as_float((uint32_t)v1.x << 16));
            o.w = cvt_fp8(__uint_as_float((uint32_t)v1.y << 16));
            wq[i] = o;
        }
    }
}

// ---------------- quantize x -> fp8 e4m3fn ----------------
__global__ void fp8lin_quant(const float4* __restrict__ x, const float* __restrict__ scales,
                             uchar4* __restrict__ xq, long n4) {
    float s = scales[0];
    long stride = (long)gridDim.x * blockDim.x;
    for (long i = blockIdx.x * (long)blockDim.x + threadIdx.x; i < n4; i += stride) {
        float4 v = x[i];
        uchar4 o;
        o.x = cvt_fp8(v.x / s); o.y = cvt_fp8(v.y / s);
        o.z = cvt_fp8(v.z / s); o.w = cvt_fp8(v.w / s);
        xq[i] = o;
    }
}

// ---- fp8 GEMM: 256x128 tile, BK=64, 4 waves, MX 32x32x64, dbuf, 2 blocks/CU ----
#define BM 256
#define BN 128
#define BK 64
#define A_BYTES 16384                 // 256 rows x 64 B
#define B_BYTES 8192                  // 128 rows x 64 B
#define BUF_BYTES (A_BYTES + B_BYTES) // 24 KiB
#define SMEM_BYTES (2 * BUF_BYTES)    // 48 KiB double-buffered -> 2 blocks/CU

__device__ __forceinline__ void gload16(const uint8_t* src, uint8_t* ldst) {
    __builtin_amdgcn_global_load_lds(
        (const __attribute__((address_space(1))) uint32_t*)(uintptr_t)src,
        (__attribute__((address_space(3))) uint32_t*)(uintptr_t)ldst, 16, 0, 0);
}

#define WAITVM(N) asm volatile("s_waitcnt vmcnt(" #N ")" ::: "memory")
#define BARRIER() do { asm volatile("" ::: "memory"); __builtin_amdgcn_s_barrier(); \
                       asm volatile("" ::: "memory"); } while (0)

// load one 32B k-fragment (two ds_read_b128 at XOR-16 swizzled granules)
#define LDFRAG(dst, base, off) do {                                    \
    i32x4 _lo = *(const i32x4*)((base) + (off));                       \
    i32x4 _hi = *(const i32x4*)((base) + ((off) ^ 16));                \
    dst[0] = _lo[0]; dst[1] = _lo[1]; dst[2] = _lo[2]; dst[3] = _lo[3];\
    dst[4] = _hi[0]; dst[5] = _hi[1]; dst[6] = _hi[2]; dst[7] = _hi[3];\
} while (0)

// unit scales: e8m0 byte 0x7f = 2^0, every byte identical so opsel-immune
#define MFMA_MX(A, B, C) __builtin_amdgcn_mfma_scale_f32_32x32x64_f8f6f4( \
    (A), (B), (C), 0, 0, 0, (int)0x7f7f7f7f, 0, (int)0x7f7f7f7f)

// min-waves/EU = 2 (256-reg budget). Forcing 4 spilled the 128-reg acc (R6).
// 4-wave blocks: 2 independent blocks/CU at the same 2-waves/SIMD register cap
// -> their barrier phases decorrelate and MFMA overlaps the other block's LDS.
__global__ __launch_bounds__(256, 2) void fp8lin_gemm(
    const uint8_t* __restrict__ Aq,    // [M,K] fp8
    const uint8_t* __restrict__ Wraw,  // original weight ptr (valid iff flag==3)
    const uint8_t* __restrict__ Wconv, // converted fp8 (valid iff flag!=3)
    const unsigned* __restrict__ flag,
    const float* __restrict__ scales,
    const float* __restrict__ bias,
    float* __restrict__ out,
    int M, int N, int K) {
    extern __shared__ __align__(16) uint8_t smem[];

    const uint8_t* __restrict__ Wq = (*flag == 3u) ? Wraw : Wconv;

    const int tid = threadIdx.x;
    const int wid = tid >> 6;
    const int lane = tid & 63;
    const int wm = wid >> 1;   // 0..1  (M-wave, 128 rows each)
    const int wn = wid & 1;    // 0..1  (N-wave, 64 cols each)

    // ---- bijective XCD swizzle: contiguous chunk of blocks per XCD ----
    const int nbx = gridDim.x;                       // 128
    const int orig = blockIdx.y * nbx + blockIdx.x;  // dispatch order
    const int cpx = (gridDim.x * gridDim.y) >> 3;    // 512
    const int swzb = (orig & 7) * cpx + (orig >> 3);
    const int brow = (swzb / nbx) * BM;
    const int bcol = (swzb % nbx) * BN;

    // ---- staging: LDS linear [row][4 granules of 16B]; granule p holds global
    // granule p ^ ((row>>1)&3)  => pre-swizzle the global source column ----
    // A: chunks c = tid + 256*j (j=0..3); B: c = tid + 256*j (j=0..1)
    const uint8_t* srcA[4];
    const uint8_t* srcB[2];
#pragma unroll
    for (int j = 0; j < 4; ++j) {
        int c = tid + 256 * j;
        int r = c >> 2;
        int sc = ((c & 3) ^ ((r >> 1) & 3)) * 16;
        srcA[j] = Aq + (size_t)(brow + r) * K + sc;
    }
#pragma unroll
    for (int j = 0; j < 2; ++j) {
        int c = tid + 256 * j;
        int r = c >> 2;
        int sc = ((c & 3) ^ ((r >> 1) & 3)) * 16;
        srcB[j] = Wq + (size_t)(bcol + r) * K + sc;
    }
    const int ldsW = wid * 1024;   // wave-uniform part of chunk*16 (lane*16 implicit)

    // ---- ds_read addressing: lane reads k-bytes [32q,32q+32) of its row ----
    const int l31 = lane & 31;
    const int q = lane >> 5;
    const int swzr = (l31 >> 1) & 3;          // row-base is mult of 32
    const int posl = (2 * q) ^ swzr;
    const int offA = (wm * 128 + l31) * 64 + posl * 16;  // + mi*2048
    const int offB = (wn * 64 + l31) * 64 + posl * 16;   // + ni*2048

    f32x16 acc[4][2];
#pragma unroll
    for (int mi = 0; mi < 4; ++mi)
#pragma unroll
        for (int ni = 0; ni < 2; ++ni)
#pragma unroll
            for (int r = 0; r < 16; ++r) acc[mi][ni][r] = 0.0f;

    auto STAGE = [&](int t, int ib) {
        size_t k0 = (size_t)t * BK;
        uint8_t* base = smem + ib * BUF_BYTES;
        gload16(srcA[0] + k0, base + ldsW);
        gload16(srcA[1] + k0, base + ldsW + 4096);
        gload16(srcA[2] + k0, base + ldsW + 8192);
        gload16(srcA[3] + k0, base + ldsW + 12288);
        gload16(srcB[0] + k0, base + A_BYTES + ldsW);
        gload16(srcB[1] + k0, base + A_BYTES + ldsW + 4096);
    };

    auto COMPUTE = [&](int ib) {
        const uint8_t* bA = smem + ib * BUF_BYTES;
        const uint8_t* bB = bA + A_BYTES;
        i32x8 a0, a1, a2, a3, b0, b1;
        LDFRAG(a0, bA, offA);
        LDFRAG(a1, bA, offA + 2048);
        LDFRAG(b0, bB, offB);
        LDFRAG(b1, bB, offB + 2048);
        __builtin_amdgcn_s_setprio(1);
        acc[0][0] = MFMA_MX(a0, b0, acc[0][0]);
        acc[1][0] = MFMA_MX(a1, b0, acc[1][0]);
        acc[0][1] = MFMA_MX(a0, b1, acc[0][1]);
        acc[1][1] = MFMA_MX(a1, b1, acc[1][1]);
        __builtin_amdgcn_s_setprio(0);
        LDFRAG(a2, bA, offA + 4096);
        LDFRAG(a3, bA, offA + 6144);
        __builtin_amdgcn_s_setprio(1);
        acc[2][0] = MFMA_MX(a2, b0, acc[2][0]);
        acc[3][0] = MFMA_MX(a3, b0, acc[3][0]);
        acc[2][1] = MFMA_MX(a2, b1, acc[2][1]);
        acc[3][1] = MFMA_MX(a3, b1, acc[3][1]);
        __builtin_amdgcn_s_setprio(0);
    };

    const int NT = K / BK;  // 64
    STAGE(0, 0);
    int cur = 0;
    for (int t = 0; t < NT - 1; ++t) {
        STAGE(t + 1, cur ^ 1);   // next tile's 6 loads issued before the wait
        WAITVM(6);               // tile t's 6 loads landed; next 6 stay in flight
        BARRIER();
        COMPUTE(cur);
        BARRIER();               // all LDS reads of buf cur retired before restaging
        cur ^= 1;
    }
    WAITVM(0);
    BARRIER();
    COMPUTE(cur);

    // ---- epilogue: 32x32 C/D layout col=lane&31, row=(reg&3)+8*(reg>>2)+4*q ----
    float s = scales[1];
    const int colg = bcol + wn * 64 + l31;
    const int rowg0 = brow + wm * 128 + 4 * q;
#pragma unroll
    for (int ni = 0; ni < 2; ++ni) {
        int col = colg + ni * 32;
        float bv = bias[col];
#pragma unroll
        for (int mi = 0; mi < 4; ++mi) {
            int rb = rowg0 + mi * 32;
#pragma unroll
            for (int reg = 0; reg < 16; ++reg) {
                int row = rb + (reg & 3) + 8 * (reg >> 2);
                __builtin_nontemporal_store(acc[mi][ni][reg] * s + bv,
                                            out + (size_t)row * N + col);
            }
        }
    }
}

extern "C" void kernel_launch(void* const* d_in, const int* in_sizes, int n_in,
                              void* d_out, int out_size, void* d_ws, size_t ws_size,
                              hipStream_t stream) {
    const float* x = (const float*)d_in[0];
    const void* w = d_in[1];
    const float* wscale = (const float*)d_in[2];
    const float* bias = (const float*)d_in[3];
    float* out = (float*)d_out;

    const int Bb = 4, S = 2048, K = 4096, N = 16384;
    const int M = Bb * S;
    const long nx = (long)M * K;
    const long nw = (long)N * K;

    unsigned* amax_bits = (unsigned*)d_ws;
    float* scales = (float*)((char*)d_ws + 16);
    unsigned* wflag = (unsigned*)((char*)d_ws + 32);
    uchar4* xq = (uchar4*)((char*)d_ws + 256);
    uchar4* wq = (uchar4*)((char*)d_ws + 256 + nx);

    fp8lin_init<<<1, 1, 0, stream>>>(amax_bits);
    fp8lin_probe<<<1, 256, 0, stream>>>((const uint32_t*)w, wflag);
    fp8lin_amax<<<2048, 256, 0, stream>>>((const float4*)x, amax_bits, nx / 4);
    fp8lin_scales<<<1, 1, 0, stream>>>(amax_bits, wscale, scales);
    fp8lin_quant<<<2048, 256, 0, stream>>>((const float4*)x, scales, xq, nx / 4);
    fp8lin_convw<<<2048, 256, 0, stream>>>(w, wflag, wq, nw / 4);

    dim3 grid(N / BN, M / BM);   // (128, 32) = 4096 blocks
    fp8lin_gemm<<<grid, 256, SMEM_BYTES, stream>>>((const uint8_t*)xq, (const uint8_t*)w,
                                                   (const uint8_t*)wq, wflag, scales, bias, out,
                                                   M, N, K);
}